// Round 4
// baseline (369.766 us; speedup 1.0000x reference)
//
#include <hip/hip_runtime.h>

// CAttention on MI355X (gfx950). Inputs float32 (per reference), output float32.
// Identity: boxsum3x3(einsum(k, x_pad)) == einsum(k, boxsum3x3(x)) -> pure attention:
//   Q = box3(x) [4096x128], K = V = normalize(x + EPS) [4096x128], softmax over keys, per batch.
// Internal ws tensors are bf16 (for MFMA): kmat (B,L,C) @0 | kT (B,C,L) @4MB | xbT (B,L,C) @8MB.

typedef short bf16x8 __attribute__((ext_vector_type(8)));
typedef float f32x4 __attribute__((ext_vector_type(4)));

__device__ __forceinline__ unsigned short f2bf(float f) {
    unsigned int u;
    __builtin_memcpy(&u, &f, 4);
    u = u + 0x7FFFu + ((u >> 16) & 1u);   // RNE
    return (unsigned short)(u >> 16);
}

// ---------------- K1: k = (x+EPS)/||x+EPS|| per pixel; store row-major and transposed ----
__global__ void prep_k(const float* __restrict__ x,
                       unsigned short* __restrict__ kmat,
                       unsigned short* __restrict__ kT) {
    const int b = blockIdx.y;
    const int l = blockIdx.x * 256 + threadIdx.x;
    const float* xb = x + (size_t)b * 128 * 4096;
    float sq = 0.f;
#pragma unroll 8
    for (int c = 0; c < 128; c++) {
        float v = xb[c * 4096 + l] + 1e-7f;
        sq += v * v;
    }
    const float inv = rsqrtf(sq);
    unsigned short* kmr = kmat + ((size_t)b * 4096 + l) * 128;
    unsigned short* ktb = kT + (size_t)b * 128 * 4096;
#pragma unroll 8
    for (int c = 0; c < 128; c++) {
        float v = (xb[c * 4096 + l] + 1e-7f) * inv;
        unsigned short h = f2bf(v);
        kmr[c] = h;              // kmat[b][l][c]
        ktb[c * 4096 + l] = h;   // kT[b][c][l]
    }
}

// ---------------- K2: xbT[b][l][c] = 3x3 zero-padded box sum of x[b][c][:][:] ------------
__global__ void prep_xb(const float* __restrict__ x,
                        unsigned short* __restrict__ xbT) {
    const int b = blockIdx.y, c = blockIdx.x, t = threadIdx.x;
    __shared__ float pl[4096];
    const float* xp = x + ((size_t)b * 128 + c) * 4096;
#pragma unroll
    for (int i = 0; i < 16; i++) pl[t + i * 256] = xp[t + i * 256];
    __syncthreads();
#pragma unroll
    for (int i = 0; i < 16; i++) {
        int l = t + i * 256;
        int p = l >> 6, q = l & 63;
        float s = 0.f;
#pragma unroll
        for (int dp = -1; dp <= 1; dp++) {
            int pp = p + dp;
            if ((unsigned)pp < 64u) {
                const float* row = &pl[pp * 64];
#pragma unroll
                for (int dq = -1; dq <= 1; dq++) {
                    int qq = q + dq;
                    if ((unsigned)qq < 64u) s += row[qq];
                }
            }
        }
        xbT[((size_t)b * 4096 + l) * 128 + c] = f2bf(s);
    }
}

// ---------------- K3: flash attention -----------------------------------------------------
// grid (64 qtiles, 4 batches), 256 threads = 4 waves, 16 queries/wave, BK=64.
#define SK_STRIDE 136   // 128 + 8 pad (bf16 elems) -> 272B rows, 16B aligned
#define SV_STRIDE 72    // 64 + 8 pad -> 144B rows
#define SP_STRIDE 72
#define SMEM_ELEMS (64 * SK_STRIDE + 128 * SV_STRIDE + 4 * 16 * SP_STRIDE)

__global__ void __launch_bounds__(256) flash_attn(
        const unsigned short* __restrict__ kmat,
        const unsigned short* __restrict__ kT,
        const unsigned short* __restrict__ xbT,
        const float* __restrict__ x,
        const float* __restrict__ mask,
        float* __restrict__ out) {
    const int b = blockIdx.y;
    const int qb = blockIdx.x;          // 64-query tile index
    const int t = threadIdx.x;
    const int wave = t >> 6, lane = t & 63;
    const int l16 = lane & 15, quad = lane >> 4;

    __shared__ __align__(16) unsigned short smem[SMEM_ELEMS];
    unsigned short* sK = smem;                                   // [64 keys][136]
    unsigned short* sV = smem + 64 * SK_STRIDE;                  // [128 ch][72]
    unsigned short* sP = smem + 64 * SK_STRIDE + 128 * SV_STRIDE + wave * 16 * SP_STRIDE;

    // zero-init LDS so any residual read is 0.0
    for (int i = t; i < SMEM_ELEMS; i += 256) smem[i] = 0;
    __syncthreads();

    // Q A-frags: A[m=lane&15][k=quad*8+j], m -> query, k -> channel
    const int qg = qb * 64 + wave * 16 + l16;
    bf16x8 aq[4];
    {
        const unsigned short* xq = xbT + ((size_t)b * 4096 + qg) * 128 + quad * 8;
#pragma unroll
        for (int cc = 0; cc < 4; cc++) aq[cc] = *(const bf16x8*)(xq + cc * 32);
    }

    f32x4 o[8];
#pragma unroll
    for (int n = 0; n < 8; n++) o[n] = (f32x4){0.f, 0.f, 0.f, 0.f};
    float mprev[4], lprev[4];
#pragma unroll
    for (int r = 0; r < 4; r++) { mprev[r] = -3.0e4f; lprev[r] = 0.f; }

    const float L2E = 1.4426950408889634f;
    const unsigned short* kmb = kmat + (size_t)b * 4096 * 128;
    const unsigned short* ktb = kT + (size_t)b * 128 * 4096;

    for (int kt0 = 0; kt0 < 4096; kt0 += 64) {
        __syncthreads();
        // stage K tile (64 keys x 128 ch), coalesced 16B per thread per iter
#pragma unroll
        for (int i = 0; i < 4; i++) {
            int e = i * 2048 + t * 8;
            int row = e >> 7, col = e & 127;
            *(bf16x8*)(sK + row * SK_STRIDE + col) =
                *(const bf16x8*)(kmb + (size_t)(kt0 + row) * 128 + col);
        }
        // stage V tile (128 ch x 64 keys) from kT
#pragma unroll
        for (int i = 0; i < 4; i++) {
            int e = i * 2048 + t * 8;
            int c = e >> 6, key = e & 63;
            *(bf16x8*)(sV + c * SV_STRIDE + key) =
                *(const bf16x8*)(ktb + (size_t)c * 4096 + kt0 + key);
        }
        __syncthreads();

        // S = Q K^T : 4 key sub-tiles x 4 c-chunks
        f32x4 s[4];
#pragma unroll
        for (int k4 = 0; k4 < 4; k4++) s[k4] = (f32x4){0.f, 0.f, 0.f, 0.f};
#pragma unroll
        for (int cc = 0; cc < 4; cc++) {
#pragma unroll
            for (int k4 = 0; k4 < 4; k4++) {
                bf16x8 bf = *(const bf16x8*)(sK + (k4 * 16 + l16) * SK_STRIDE + cc * 32 + quad * 8);
                s[k4] = __builtin_amdgcn_mfma_f32_16x16x32_bf16(aq[cc], bf, s[k4], 0, 0, 0);
            }
        }

        // online softmax: lane holds rows quad*4+r, col l16 (C/D layout, HW-verified)
        float mt[4];
#pragma unroll
        for (int r = 0; r < 4; r++)
            mt[r] = fmaxf(fmaxf(s[0][r], s[1][r]), fmaxf(s[2][r], s[3][r]));
#pragma unroll
        for (int off = 1; off < 16; off <<= 1)
#pragma unroll
            for (int r = 0; r < 4; r++) mt[r] = fmaxf(mt[r], __shfl_xor(mt[r], off));
        float alpha[4], rs[4];
#pragma unroll
        for (int r = 0; r < 4; r++) {
            float mn = fmaxf(mprev[r], mt[r]);
            alpha[r] = exp2f((mprev[r] - mn) * L2E);
            mprev[r] = mn;
            rs[r] = 0.f;
        }
#pragma unroll
        for (int k4 = 0; k4 < 4; k4++)
#pragma unroll
            for (int r = 0; r < 4; r++) {
                float p = exp2f((s[k4][r] - mprev[r]) * L2E);
                s[k4][r] = p;
                rs[r] += p;
            }
#pragma unroll
        for (int off = 1; off < 16; off <<= 1)
#pragma unroll
            for (int r = 0; r < 4; r++) rs[r] += __shfl_xor(rs[r], off);
#pragma unroll
        for (int r = 0; r < 4; r++) lprev[r] = lprev[r] * alpha[r] + rs[r];
#pragma unroll
        for (int n = 0; n < 8; n++)
#pragma unroll
            for (int r = 0; r < 4; r++) o[n][r] *= alpha[r];

        // P: C/D layout -> A layout via per-wave LDS round-trip (m120 pattern).
#pragma unroll
        for (int k4 = 0; k4 < 4; k4++)
#pragma unroll
            for (int r = 0; r < 4; r++)
                sP[(quad * 4 + r) * SP_STRIDE + k4 * 16 + l16] = f2bf(s[k4][r]);
        asm volatile("" ::: "memory");
        __threadfence_block();
        bf16x8 pa[2];
#pragma unroll
        for (int kc = 0; kc < 2; kc++)
            pa[kc] = *(const bf16x8*)(sP + l16 * SP_STRIDE + kc * 32 + quad * 8);
        asm volatile("" ::: "memory");

        // O += P V : 8 channel tiles, 2 key chunks
#pragma unroll
        for (int kc = 0; kc < 2; kc++)
#pragma unroll
            for (int n = 0; n < 8; n++) {
                bf16x8 bf = *(const bf16x8*)(sV + (n * 16 + l16) * SV_STRIDE + kc * 32 + quad * 8);
                o[n] = __builtin_amdgcn_mfma_f32_16x16x32_bf16(pa[kc], bf, o[n], 0, 0, 0);
            }
    }

    // epilogue: normalize, transpose through LDS as f32, blend with mask, float4 stores
    __syncthreads();
    float* sO = reinterpret_cast<float*>(smem);  // [128 ch][72] f32 = 36864 B <= 45056 B
#pragma unroll
    for (int n = 0; n < 8; n++)
#pragma unroll
        for (int r = 0; r < 4; r++) {
            sO[(n * 16 + l16) * SV_STRIDE + wave * 16 + quad * 4 + r] =
                o[n][r] / fmaxf(lprev[r], 1e-30f);
        }
    __syncthreads();
    {
        const int c = t >> 1, half = t & 1;
        const int q0 = qb * 64 + half * 32;
        const float* xr = x + ((size_t)b * 128 + c) * 4096 + q0;
        const float* mr = mask + (size_t)b * 4096 + q0;
        float* outr = out + ((size_t)b * 128 + c) * 4096 + q0;
#pragma unroll
        for (int i = 0; i < 8; i++) {
            int j0 = i * 4;
            f32x4 ov = *(const f32x4*)(sO + c * SV_STRIDE + half * 32 + j0);
            f32x4 xv = *(const f32x4*)(xr + j0);
            f32x4 mv = *(const f32x4*)(mr + j0);
            f32x4 res;
#pragma unroll
            for (int j = 0; j < 4; j++)
                res[j] = ov[j] * (1.f - mv[j]) * (1.f / 9.f) + xv[j] * mv[j];
            *(f32x4*)(outr + j0) = res;
        }
    }
}

extern "C" void kernel_launch(void* const* d_in, const int* in_sizes, int n_in,
                              void* d_out, int out_size, void* d_ws, size_t ws_size,
                              hipStream_t stream) {
    const float* x = (const float*)d_in[0];     // f32 (4,128,64,64)
    const float* mask = (const float*)d_in[1];  // f32 (4,1,64,64)
    float* out = (float*)d_out;                 // f32 (4,128,64,64)
    char* ws = (char*)d_ws;
    unsigned short* kmat = (unsigned short*)(ws);
    unsigned short* kT = (unsigned short*)(ws + (size_t)4 * 1024 * 1024);
    unsigned short* xbT = (unsigned short*)(ws + (size_t)8 * 1024 * 1024);

    if (ws_size < (size_t)12 * 1024 * 1024) return;  // diagnostic guard

    prep_k<<<dim3(16, 4), 256, 0, stream>>>(x, kmat, kT);
    prep_xb<<<dim3(128, 4), 256, 0, stream>>>(x, xbT);
    flash_attn<<<dim3(64, 4), 256, 0, stream>>>(kmat, kT, xbT, x, mask, out);
}

// Round 5
// 256.832 us; speedup vs baseline: 1.4397x; 1.4397x over previous
//
#include <hip/hip_runtime.h>

// CAttention on MI355X (gfx950). Inputs f32, output f32.
// Identity: boxsum3x3(einsum(k, x_pad)) == einsum(k, boxsum3x3(x)) -> pure attention:
//   Q = box3(x) [4096x128], K = V = normalize(x + EPS) [4096x128], softmax over keys, per batch.
// Round 5: split-K flash (S=4 -> 1024 blocks, 4/CU), sP aliases sK (35.8KB LDS),
// register prefetch pipeline, LDS-staged coalesced prep writes, combine kernel.
// ws: kmat bf16 @0 | kT bf16 @4M | xbT bf16 @8M | ml f32 @12M | opart f32 @12.5M.

typedef short bf16x8 __attribute__((ext_vector_type(8)));
typedef float f32x4 __attribute__((ext_vector_type(4)));

#define L2E 1.4426950408889634f

__device__ __forceinline__ unsigned short f2bf(float f) {
    unsigned int u;
    __builtin_memcpy(&u, &f, 4);
    u = u + 0x7FFFu + ((u >> 16) & 1u);   // RNE
    return (unsigned short)(u >> 16);
}

// ---------------- K1: k = (x+EPS)/||x+EPS||; kmat [b][l][c], kT [b][c][l] ----------------
// grid (64, B) x 256: block handles 64 l; wave w covers c in [w*32, w*32+32).
__global__ void prep_k(const float* __restrict__ x,
                       unsigned short* __restrict__ kmat,
                       unsigned short* __restrict__ kT) {
    const int b = blockIdx.y, l0 = blockIdx.x * 64, t = threadIdx.x;
    const int wave = t >> 6, lane = t & 63;
    const float* xb = x + (size_t)b * 128 * 4096;
    __shared__ float sqp[256];
    __shared__ __align__(16) unsigned short sT[64 * 136];

    float xv[32];
    float sq = 0.f;
#pragma unroll
    for (int i = 0; i < 32; i++) {
        int c = wave * 32 + i;
        float v = xb[(size_t)c * 4096 + l0 + lane] + 1e-7f;
        xv[i] = v;
        sq += v * v;
    }
    sqp[t] = sq;
    __syncthreads();
    const float inv = rsqrtf(sqp[lane] + sqp[64 + lane] + sqp[128 + lane] + sqp[192 + lane]);

    unsigned int* sT32 = (unsigned int*)sT;
#pragma unroll
    for (int i = 0; i < 16; i++) {
        int c = wave * 32 + i * 2;
        unsigned int pack = (unsigned int)f2bf(xv[2 * i] * inv) |
                            ((unsigned int)f2bf(xv[2 * i + 1] * inv) << 16);
        sT32[(lane * 136 + c) >> 1] = pack;
    }
    __syncthreads();
    // kmat rows, coalesced 16B
#pragma unroll
    for (int i = 0; i < 4; i++) {
        int e = i * 2048 + t * 8, row = e >> 7, col = e & 127;
        *(bf16x8*)(kmat + ((size_t)b * 4096 + l0 + row) * 128 + col) =
            *(const bf16x8*)(sT + row * 136 + col);
    }
    // kT: per c one 128B wave store
    unsigned short* ktb = kT + (size_t)b * 128 * 4096;
#pragma unroll
    for (int i = 0; i < 32; i++) {
        int c = wave * 32 + i;
        ktb[(size_t)c * 4096 + l0 + lane] = sT[lane * 136 + c];
    }
}

// ---------------- K2: xbT[b][l][c] = 3x3 zero-padded box sum -----------------------------
// grid (64, B) x 256: block = one p-row (64 q) across all 128 c.
__global__ void prep_xb(const float* __restrict__ x,
                        unsigned short* __restrict__ xbT) {
    const int b = blockIdx.y, p = blockIdx.x, t = threadIdx.x;
    __shared__ float sX[8][3][66];
    __shared__ __align__(16) unsigned short sQ[64 * 136];

    for (int c0 = 0; c0 < 128; c0 += 8) {
        __syncthreads();
#pragma unroll
        for (int i = 0; i < 6; i++) {
            int j = t + i * 256;                 // 0..1535 = 8c x 3r x 64q
            int cc = j / 192, rem = j % 192;
            int r = rem >> 6, q = rem & 63;
            int pp = p + r - 1;
            float v = 0.f;
            if ((unsigned)pp < 64u)
                v = x[((size_t)b * 128 + c0 + cc) * 4096 + pp * 64 + q];
            sX[cc][r][1 + q] = v;
        }
        if (t < 48) {                            // zero left/right borders
            int cc = t / 6, r = (t % 6) >> 1, side = t & 1;
            sX[cc][r][side * 65] = 0.f;
        }
        __syncthreads();
#pragma unroll
        for (int h = 0; h < 2; h++) {
            int idx = t + h * 256;               // 0..511 = 8c x 64q
            int cc = idx >> 6, q = idx & 63;
            float s = 0.f;
#pragma unroll
            for (int r = 0; r < 3; r++)
                s += sX[cc][r][q] + sX[cc][r][q + 1] + sX[cc][r][q + 2];
            sQ[q * 136 + c0 + cc] = f2bf(s);
        }
    }
    __syncthreads();
#pragma unroll
    for (int i = 0; i < 4; i++) {
        int e = i * 2048 + t * 8, row = e >> 7, col = e & 127;
        *(bf16x8*)(xbT + ((size_t)b * 4096 + p * 64 + row) * 128 + col) =
            *(const bf16x8*)(sQ + row * 136 + col);
    }
}

// ---------------- K3: split-K flash attention --------------------------------------------
// grid (64 qtiles, B, S), 256 thr = 4 waves, 16 q/wave, BK=64 keys/iter.
#define SK_STRIDE 136   // 272B rows (16B-mult)
#define SV_STRIDE 72    // 144B rows
#define SP_STRIDE 72
#define SMEM_ELEMS (64 * SK_STRIDE + 128 * SV_STRIDE)   // 17920 u16 = 35840 B

__global__ void __launch_bounds__(256, 4) flash_attn(
        const unsigned short* __restrict__ kmat,
        const unsigned short* __restrict__ kT,
        const unsigned short* __restrict__ xbT,
        float* __restrict__ opart,
        float* __restrict__ ml) {
    const int b = blockIdx.y, qb = blockIdx.x, split = blockIdx.z;
    const int nsplit = gridDim.z;
    const int nk = 4096 / nsplit, kt_base = split * nk, NIT = nk >> 6;
    const int t = threadIdx.x;
    const int wave = t >> 6, lane = t & 63;
    const int l16 = lane & 15, quad = lane >> 4;

    __shared__ __align__(16) unsigned short smem[SMEM_ELEMS];
    unsigned short* sK = smem;                               // [64 keys][136]
    unsigned short* sV = smem + 64 * SK_STRIDE;              // [128 ch][72]
    unsigned short* sP = smem + wave * 16 * SP_STRIDE;       // aliases sK (dead after QK^T)

    // Q A-frags: A[m=l16][k=quad*8+j]
    const int qg = qb * 64 + wave * 16 + l16;
    bf16x8 aq[4];
    {
        const unsigned short* xq = xbT + ((size_t)b * 4096 + qg) * 128 + quad * 8;
#pragma unroll
        for (int cc = 0; cc < 4; cc++) aq[cc] = *(const bf16x8*)(xq + cc * 32);
    }

    f32x4 o[8];
#pragma unroll
    for (int n = 0; n < 8; n++) o[n] = (f32x4){0.f, 0.f, 0.f, 0.f};
    float mprev[4], lprev[4];
#pragma unroll
    for (int r = 0; r < 4; r++) { mprev[r] = -3.0e4f; lprev[r] = 0.f; }

    const unsigned short* kmb = kmat + (size_t)b * 4096 * 128;
    const unsigned short* ktb = kT + (size_t)b * 128 * 4096;

    // prefetch registers
    bf16x8 kreg[4], vreg[4];
    {
        const int kt0 = kt_base;
#pragma unroll
        for (int i = 0; i < 4; i++) {
            int e = i * 2048 + t * 8;
            kreg[i] = *(const bf16x8*)(kmb + (size_t)(kt0 + (e >> 7)) * 128 + (e & 127));
            vreg[i] = *(const bf16x8*)(ktb + (size_t)(e >> 6) * 4096 + kt0 + (e & 63));
        }
    }

    for (int it = 0; it < NIT; it++) {
        __syncthreads();                         // (A) prior iter LDS reads done
#pragma unroll
        for (int i = 0; i < 4; i++) {
            int e = i * 2048 + t * 8;
            *(bf16x8*)(sK + (e >> 7) * SK_STRIDE + (e & 127)) = kreg[i];
            *(bf16x8*)(sV + (e >> 6) * SV_STRIDE + (e & 63)) = vreg[i];
        }
        __syncthreads();                         // (B) tiles visible
        if (it + 1 < NIT) {
            const int kt0 = kt_base + (it + 1) * 64;
#pragma unroll
            for (int i = 0; i < 4; i++) {
                int e = i * 2048 + t * 8;
                kreg[i] = *(const bf16x8*)(kmb + (size_t)(kt0 + (e >> 7)) * 128 + (e & 127));
                vreg[i] = *(const bf16x8*)(ktb + (size_t)(e >> 6) * 4096 + kt0 + (e & 63));
            }
        }

        // S = Q K^T
        f32x4 s[4];
#pragma unroll
        for (int k4 = 0; k4 < 4; k4++) s[k4] = (f32x4){0.f, 0.f, 0.f, 0.f};
#pragma unroll
        for (int cc = 0; cc < 4; cc++) {
#pragma unroll
            for (int k4 = 0; k4 < 4; k4++) {
                bf16x8 bf = *(const bf16x8*)(sK + (k4 * 16 + l16) * SK_STRIDE + cc * 32 + quad * 8);
                s[k4] = __builtin_amdgcn_mfma_f32_16x16x32_bf16(aq[cc], bf, s[k4], 0, 0, 0);
            }
        }
        __syncthreads();                         // (C) sK dead -> sP alias safe

        // online softmax (lane holds rows quad*4+r, col l16)
        float mt[4];
#pragma unroll
        for (int r = 0; r < 4; r++)
            mt[r] = fmaxf(fmaxf(s[0][r], s[1][r]), fmaxf(s[2][r], s[3][r]));
#pragma unroll
        for (int off = 1; off < 16; off <<= 1)
#pragma unroll
            for (int r = 0; r < 4; r++) mt[r] = fmaxf(mt[r], __shfl_xor(mt[r], off));
        float alpha[4], rs[4];
#pragma unroll
        for (int r = 0; r < 4; r++) {
            float mn = fmaxf(mprev[r], mt[r]);
            alpha[r] = exp2f((mprev[r] - mn) * L2E);
            mprev[r] = mn;
            rs[r] = 0.f;
        }
#pragma unroll
        for (int k4 = 0; k4 < 4; k4++)
#pragma unroll
            for (int r = 0; r < 4; r++) {
                float p = exp2f((s[k4][r] - mprev[r]) * L2E);
                s[k4][r] = p;
                rs[r] += p;
            }
#pragma unroll
        for (int off = 1; off < 16; off <<= 1)
#pragma unroll
            for (int r = 0; r < 4; r++) rs[r] += __shfl_xor(rs[r], off);
#pragma unroll
        for (int r = 0; r < 4; r++) lprev[r] = lprev[r] * alpha[r] + rs[r];
#pragma unroll
        for (int n = 0; n < 8; n++)
#pragma unroll
            for (int r = 0; r < 4; r++) o[n][r] *= alpha[r];

        // P: C/D -> A layout via per-wave LDS round-trip
#pragma unroll
        for (int k4 = 0; k4 < 4; k4++)
#pragma unroll
            for (int r = 0; r < 4; r++)
                sP[(quad * 4 + r) * SP_STRIDE + k4 * 16 + l16] = f2bf(s[k4][r]);
        asm volatile("" ::: "memory");
        __threadfence_block();
        bf16x8 pa[2];
#pragma unroll
        for (int kc = 0; kc < 2; kc++)
            pa[kc] = *(const bf16x8*)(sP + l16 * SP_STRIDE + kc * 32 + quad * 8);
        asm volatile("" ::: "memory");

        // O += P V
#pragma unroll
        for (int kc = 0; kc < 2; kc++)
#pragma unroll
            for (int n = 0; n < 8; n++) {
                bf16x8 bf = *(const bf16x8*)(sV + (n * 16 + l16) * SV_STRIDE + kc * 32 + quad * 8);
                o[n] = __builtin_amdgcn_mfma_f32_16x16x32_bf16(pa[kc], bf, o[n], 0, 0, 0);
            }
    }

    // epilogue: write m,l and unnormalized O partial (c-major)
    __syncthreads();
    if (l16 == 0) {
#pragma unroll
        for (int r = 0; r < 4; r++) {
            int q = qb * 64 + wave * 16 + quad * 4 + r;
            *(float2*)(ml + ((size_t)(split * 4 + b) * 4096 + q) * 2) =
                make_float2(mprev[r], lprev[r]);
        }
    }
    float* sO = reinterpret_cast<float*>(smem);  // [128 ch][68] f32 = 34816 B
#pragma unroll
    for (int n = 0; n < 8; n++)
#pragma unroll
        for (int r = 0; r < 4; r++)
            sO[(n * 16 + l16) * 68 + wave * 16 + quad * 4 + r] = o[n][r];
    __syncthreads();
#pragma unroll
    for (int i = 0; i < 8; i++) {
        int c = (t >> 4) + i * 16, qj = (t & 15) * 4;
        *(f32x4*)(opart + ((size_t)(split * 4 + b) * 128 + c) * 4096 + qb * 64 + qj) =
            *(const f32x4*)(sO + c * 68 + qj);
    }
}

// ---------------- K4: combine splits + mask blend ----------------------------------------
// grid (64, B) x 256: block = (qtile, batch).
__global__ void combine(const float* __restrict__ opart,
                        const float* __restrict__ ml,
                        const float* __restrict__ x,
                        const float* __restrict__ mask,
                        float* __restrict__ out, int S) {
    const int b = blockIdx.y, qb = blockIdx.x, t = threadIdx.x;
    __shared__ float w[4][64];
    __shared__ float Linv[64];
    if (t < 64) {
        int q = qb * 64 + t;
        float m[4], l[4], M = -3.0e38f;
        for (int s = 0; s < S; s++) {
            float2 v = *(const float2*)(ml + ((size_t)(s * 4 + b) * 4096 + q) * 2);
            m[s] = v.x; l[s] = v.y;
            M = fmaxf(M, v.x);
        }
        float L = 0.f;
        for (int s = 0; s < S; s++) {
            float ws = exp2f((m[s] - M) * L2E);
            w[s][t] = ws;
            L += ws * l[s];
        }
        Linv[t] = 1.f / L;
    }
    __syncthreads();
#pragma unroll
    for (int i = 0; i < 8; i++) {
        int c = (t >> 4) + i * 16, qj = (t & 15) * 4;
        size_t qoff = (size_t)qb * 64 + qj;
        f32x4 acc = (f32x4){0.f, 0.f, 0.f, 0.f};
        for (int s = 0; s < S; s++) {
            f32x4 p = *(const f32x4*)(opart + ((size_t)(s * 4 + b) * 128 + c) * 4096 + qoff);
#pragma unroll
            for (int j = 0; j < 4; j++) acc[j] += w[s][qj + j] * p[j];
        }
        f32x4 xv = *(const f32x4*)(x + ((size_t)b * 128 + c) * 4096 + qoff);
        f32x4 mv = *(const f32x4*)(mask + (size_t)b * 4096 + qoff);
        f32x4 res;
#pragma unroll
        for (int j = 0; j < 4; j++)
            res[j] = acc[j] * Linv[qj + j] * (1.f - mv[j]) * (1.f / 9.f) + xv[j] * mv[j];
        *(f32x4*)(out + ((size_t)b * 128 + c) * 4096 + qoff) = res;
    }
}

extern "C" void kernel_launch(void* const* d_in, const int* in_sizes, int n_in,
                              void* d_out, int out_size, void* d_ws, size_t ws_size,
                              hipStream_t stream) {
    const float* x = (const float*)d_in[0];     // f32 (4,128,64,64)
    const float* mask = (const float*)d_in[1];  // f32 (4,1,64,64)
    float* out = (float*)d_out;                 // f32 (4,128,64,64)
    char* ws = (char*)d_ws;
    unsigned short* kmat = (unsigned short*)(ws);
    unsigned short* kT   = (unsigned short*)(ws + (size_t)4 * 1024 * 1024);
    unsigned short* xbT  = (unsigned short*)(ws + (size_t)8 * 1024 * 1024);
    float* ml    = (float*)(ws + (size_t)12 * 1024 * 1024);
    float* opart = (float*)(ws + (size_t)12 * 1024 * 1024 + 512 * 1024);

    // adaptive split count based on workspace (opart = S * 8 MiB + 0.5 MiB ml)
    int S;
    if (ws_size >= (size_t)46661632) S = 4;
    else if (ws_size >= (size_t)29884416) S = 2;
    else if (ws_size >= (size_t)21495808) S = 1;
    else return;

    prep_k<<<dim3(64, 4), 256, 0, stream>>>(x, kmat, kT);
    prep_xb<<<dim3(64, 4), 256, 0, stream>>>(x, xbT);
    flash_attn<<<dim3(64, 4, S), 256, 0, stream>>>(kmat, kT, xbT, opart, ml);
    combine<<<dim3(64, 4), 256, 0, stream>>>(opart, ml, x, mask, out, S);
}

// Round 6
// 168.327 us; speedup vs baseline: 2.1967x; 1.5258x over previous
//
#include <hip/hip_runtime.h>

// CAttention on MI355X (gfx950). Inputs f32, output f32.
// Q = box3(x)*log2(e) [4096x128], K = V = normalize(x+EPS), softmax over keys, per batch.
// Round 6: fixed-max softmax (m=0, scores bounded), M=32 rows/wave (128q blocks),
// XCD-aware swizzle (combo = id & (4S-1) -> one XCD per (b,split)), S=4 split-K.
// ws: kmat bf16 @0 | kT bf16 @4M | xbT bf16 @8M | lsum f32 @12M | opart f32 @12M+512K.

typedef short bf16x8 __attribute__((ext_vector_type(8)));
typedef float f32x4 __attribute__((ext_vector_type(4)));

#define L2E 1.4426950408889634f

__device__ __forceinline__ unsigned short f2bf(float f) {
    unsigned int u;
    __builtin_memcpy(&u, &f, 4);
    u = u + 0x7FFFu + ((u >> 16) & 1u);   // RNE
    return (unsigned short)(u >> 16);
}

// ---------------- K1: k = (x+EPS)/||x+EPS||; kmat [b][l][c], kT [b][c][l] ----------------
__global__ void prep_k(const float* __restrict__ x,
                       unsigned short* __restrict__ kmat,
                       unsigned short* __restrict__ kT) {
    const int b = blockIdx.y, l0 = blockIdx.x * 64, t = threadIdx.x;
    const int wave = t >> 6, lane = t & 63;
    const float* xb = x + (size_t)b * 128 * 4096;
    __shared__ float sqp[256];
    __shared__ __align__(16) unsigned short sT[64 * 136];

    float xv[32];
    float sq = 0.f;
#pragma unroll
    for (int i = 0; i < 32; i++) {
        int c = wave * 32 + i;
        float v = xb[(size_t)c * 4096 + l0 + lane] + 1e-7f;
        xv[i] = v;
        sq += v * v;
    }
    sqp[t] = sq;
    __syncthreads();
    const float inv = rsqrtf(sqp[lane] + sqp[64 + lane] + sqp[128 + lane] + sqp[192 + lane]);

    unsigned int* sT32 = (unsigned int*)sT;
#pragma unroll
    for (int i = 0; i < 16; i++) {
        int c = wave * 32 + i * 2;
        unsigned int pack = (unsigned int)f2bf(xv[2 * i] * inv) |
                            ((unsigned int)f2bf(xv[2 * i + 1] * inv) << 16);
        sT32[(lane * 136 + c) >> 1] = pack;
    }
    __syncthreads();
#pragma unroll
    for (int i = 0; i < 4; i++) {
        int e = i * 2048 + t * 8, row = e >> 7, col = e & 127;
        *(bf16x8*)(kmat + ((size_t)b * 4096 + l0 + row) * 128 + col) =
            *(const bf16x8*)(sT + row * 136 + col);
    }
    unsigned short* ktb = kT + (size_t)b * 128 * 4096;
#pragma unroll
    for (int i = 0; i < 32; i++) {
        int c = wave * 32 + i;
        ktb[(size_t)c * 4096 + l0 + lane] = sT[lane * 136 + c];
    }
}

// ---------------- K2: xbT[b][l][c] = L2E * 3x3 zero-padded box sum -----------------------
__global__ void prep_xb(const float* __restrict__ x,
                        unsigned short* __restrict__ xbT) {
    const int b = blockIdx.y, p = blockIdx.x, t = threadIdx.x;
    __shared__ float sX[8][3][66];
    __shared__ __align__(16) unsigned short sQ[64 * 136];

    for (int c0 = 0; c0 < 128; c0 += 8) {
        __syncthreads();
#pragma unroll
        for (int i = 0; i < 6; i++) {
            int j = t + i * 256;
            int cc = j / 192, rem = j % 192;
            int r = rem >> 6, q = rem & 63;
            int pp = p + r - 1;
            float v = 0.f;
            if ((unsigned)pp < 64u)
                v = x[((size_t)b * 128 + c0 + cc) * 4096 + pp * 64 + q];
            sX[cc][r][1 + q] = v;
        }
        if (t < 48) {
            int cc = t / 6, r = (t % 6) >> 1, side = t & 1;
            sX[cc][r][side * 65] = 0.f;
        }
        __syncthreads();
#pragma unroll
        for (int h = 0; h < 2; h++) {
            int idx = t + h * 256;
            int cc = idx >> 6, q = idx & 63;
            float s = 0.f;
#pragma unroll
            for (int r = 0; r < 3; r++)
                s += sX[cc][r][q] + sX[cc][r][q + 1] + sX[cc][r][q + 2];
            sQ[q * 136 + c0 + cc] = f2bf(s * L2E);   // fold log2(e) into Q
        }
    }
    __syncthreads();
#pragma unroll
    for (int i = 0; i < 4; i++) {
        int e = i * 2048 + t * 8, row = e >> 7, col = e & 127;
        *(bf16x8*)(xbT + ((size_t)b * 4096 + p * 64 + row) * 128 + col) =
            *(const bf16x8*)(sQ + row * 136 + col);
    }
}

// ---------------- K3: split-K flash, fixed max m=0, M=32/wave ----------------------------
// grid 1D 32*4*S: combo = id % (4S) (b=combo&3, split=combo>>2), qb = id/(4S).
// For S=4 all 32 blocks of a combo share id%16 -> same XCD under round-robin.
#define SK_STRIDE 136   // 272B rows
#define SV_STRIDE 72    // 144B rows
#define SP_STRIDE 72
#define SK_ELEMS (64 * SK_STRIDE)      // 8704
#define SV_ELEMS (128 * SV_STRIDE)     // 9216
#define SP_ELEMS (4 * 32 * SP_STRIDE)  // 9216
#define SMEM_ELEMS (SK_ELEMS + SV_ELEMS + SP_ELEMS)  // 27136 u16 = 54272 B

__global__ void __launch_bounds__(256, 2) flash_attn(
        const unsigned short* __restrict__ kmat,
        const unsigned short* __restrict__ kT,
        const unsigned short* __restrict__ xbT,
        float* __restrict__ opart,
        float* __restrict__ lsum,
        int nsplit) {
    const int combo = blockIdx.x & (4 * nsplit - 1);
    const int qb = blockIdx.x / (4 * nsplit);    // 0..31, 128-query tile
    const int b = combo & 3, split = combo >> 2;
    const int nk = 4096 / nsplit, kt_base = split * nk, NIT = nk >> 6;
    const int t = threadIdx.x;
    const int wave = t >> 6, lane = t & 63;
    const int l16 = lane & 15, quad = lane >> 4;

    __shared__ __align__(16) unsigned short smem[SMEM_ELEMS];
    unsigned short* sK = smem;                         // [64 keys][136]
    unsigned short* sV = smem + SK_ELEMS;              // [128 ch][72]
    unsigned short* sP = smem + SK_ELEMS + SV_ELEMS + wave * 32 * SP_STRIDE;  // per-wave

    // Q A-frags for two 16-row blocks: A[m=l16][k=quad*8+j]
    bf16x8 aq[2][4];
#pragma unroll
    for (int h = 0; h < 2; h++) {
        const unsigned short* xq =
            xbT + ((size_t)b * 4096 + qb * 128 + wave * 32 + h * 16 + l16) * 128 + quad * 8;
#pragma unroll
        for (int cc = 0; cc < 4; cc++) aq[h][cc] = *(const bf16x8*)(xq + cc * 32);
    }

    f32x4 o[2][8];
#pragma unroll
    for (int h = 0; h < 2; h++)
#pragma unroll
        for (int n = 0; n < 8; n++) o[h][n] = (f32x4){0.f, 0.f, 0.f, 0.f};
    float rs[2][4] = {{0.f, 0.f, 0.f, 0.f}, {0.f, 0.f, 0.f, 0.f}};

    const unsigned short* kmb = kmat + (size_t)b * 4096 * 128;
    const unsigned short* ktb = kT + (size_t)b * 128 * 4096;

    bf16x8 kreg[4], vreg[4];
#pragma unroll
    for (int i = 0; i < 4; i++) {
        int e = i * 2048 + t * 8;
        kreg[i] = *(const bf16x8*)(kmb + (size_t)(kt_base + (e >> 7)) * 128 + (e & 127));
        vreg[i] = *(const bf16x8*)(ktb + (size_t)(e >> 6) * 4096 + kt_base + (e & 63));
    }

    for (int it = 0; it < NIT; it++) {
        __syncthreads();                         // prior iter's sK/sV reads done
#pragma unroll
        for (int i = 0; i < 4; i++) {
            int e = i * 2048 + t * 8;
            *(bf16x8*)(sK + (e >> 7) * SK_STRIDE + (e & 127)) = kreg[i];
            *(bf16x8*)(sV + (e >> 6) * SV_STRIDE + (e & 63)) = vreg[i];
        }
        __syncthreads();                         // tiles visible
        if (it + 1 < NIT) {
            const int kt0 = kt_base + (it + 1) * 64;
#pragma unroll
            for (int i = 0; i < 4; i++) {
                int e = i * 2048 + t * 8;
                kreg[i] = *(const bf16x8*)(kmb + (size_t)(kt0 + (e >> 7)) * 128 + (e & 127));
                vreg[i] = *(const bf16x8*)(ktb + (size_t)(e >> 6) * 4096 + kt0 + (e & 63));
            }
        }

        // S = Q K^T (s holds log2-scale scores; L2E folded into Q)
        f32x4 s[2][4];
#pragma unroll
        for (int h = 0; h < 2; h++)
#pragma unroll
            for (int k4 = 0; k4 < 4; k4++) s[h][k4] = (f32x4){0.f, 0.f, 0.f, 0.f};
#pragma unroll
        for (int cc = 0; cc < 4; cc++) {
#pragma unroll
            for (int k4 = 0; k4 < 4; k4++) {
                bf16x8 bf = *(const bf16x8*)(sK + (k4 * 16 + l16) * SK_STRIDE + cc * 32 + quad * 8);
#pragma unroll
                for (int h = 0; h < 2; h++)
                    s[h][k4] = __builtin_amdgcn_mfma_f32_16x16x32_bf16(aq[h][cc], bf, s[h][k4], 0, 0, 0);
            }
        }

        // fixed-max softmax: p = 2^s directly; accumulate row-sum per lane
#pragma unroll
        for (int h = 0; h < 2; h++)
#pragma unroll
            for (int k4 = 0; k4 < 4; k4++)
#pragma unroll
                for (int r = 0; r < 4; r++) {
                    float p = exp2f(s[h][k4][r]);
                    s[h][k4][r] = p;
                    rs[h][r] += p;
                }

        // P: C/D -> A layout via per-wave-private LDS round-trip
#pragma unroll
        for (int h = 0; h < 2; h++)
#pragma unroll
            for (int k4 = 0; k4 < 4; k4++)
#pragma unroll
                for (int r = 0; r < 4; r++)
                    sP[(h * 16 + quad * 4 + r) * SP_STRIDE + k4 * 16 + l16] = f2bf(s[h][k4][r]);
        asm volatile("" ::: "memory");
        __threadfence_block();
        bf16x8 pa[2][2];
#pragma unroll
        for (int h = 0; h < 2; h++)
#pragma unroll
            for (int kc = 0; kc < 2; kc++)
                pa[h][kc] = *(const bf16x8*)(sP + (h * 16 + l16) * SP_STRIDE + kc * 32 + quad * 8);
        asm volatile("" ::: "memory");

        // O += P V : V-frag shared across both row-blocks
#pragma unroll
        for (int kc = 0; kc < 2; kc++)
#pragma unroll
            for (int n = 0; n < 8; n++) {
                bf16x8 bf = *(const bf16x8*)(sV + (n * 16 + l16) * SV_STRIDE + kc * 32 + quad * 8);
#pragma unroll
                for (int h = 0; h < 2; h++)
                    o[h][n] = __builtin_amdgcn_mfma_f32_16x16x32_bf16(pa[h][kc], bf, o[h][n], 0, 0, 0);
            }
    }

    // l: one butterfly over the 16 l16-lanes at the end
#pragma unroll
    for (int off = 1; off < 16; off <<= 1)
#pragma unroll
        for (int h = 0; h < 2; h++)
#pragma unroll
            for (int r = 0; r < 4; r++) rs[h][r] += __shfl_xor(rs[h][r], off);
    if (l16 == 0) {
#pragma unroll
        for (int h = 0; h < 2; h++)
#pragma unroll
            for (int r = 0; r < 4; r++) {
                int q = qb * 128 + wave * 32 + h * 16 + quad * 4 + r;
                lsum[(size_t)(split * 4 + b) * 4096 + q] = rs[h][r];
            }
    }

    // O partial store via LDS transpose, two 64-q passes
    float* sO = reinterpret_cast<float*>(smem);  // [128 ch][68] f32 = 34816 B
#pragma unroll
    for (int half = 0; half < 2; half++) {
        __syncthreads();
        if ((wave >> 1) == half) {
#pragma unroll
            for (int h = 0; h < 2; h++)
#pragma unroll
                for (int n = 0; n < 8; n++)
#pragma unroll
                    for (int r = 0; r < 4; r++)
                        sO[(n * 16 + l16) * 68 + (wave & 1) * 32 + h * 16 + quad * 4 + r] =
                            o[h][n][r];
        }
        __syncthreads();
#pragma unroll
        for (int i = 0; i < 8; i++) {
            int c = (t >> 4) + i * 16, qj = (t & 15) * 4;
            *(f32x4*)(opart + ((size_t)(split * 4 + b) * 128 + c) * 4096 +
                      qb * 128 + half * 64 + qj) = *(const f32x4*)(sO + c * 68 + qj);
        }
    }
}

// ---------------- K4: combine splits (plain sums, m=0) + mask blend ----------------------
__global__ void combine(const float* __restrict__ opart,
                        const float* __restrict__ lsum,
                        const float* __restrict__ x,
                        const float* __restrict__ mask,
                        float* __restrict__ out, int S) {
    const int b = blockIdx.y, qb = blockIdx.x, t = threadIdx.x;
    __shared__ float Linv[64];
    if (t < 64) {
        int q = qb * 64 + t;
        float L = 0.f;
        for (int s = 0; s < S; s++) L += lsum[(size_t)(s * 4 + b) * 4096 + q];
        Linv[t] = 1.f / fmaxf(L, 1e-37f);
    }
    __syncthreads();
#pragma unroll
    for (int i = 0; i < 8; i++) {
        int c = (t >> 4) + i * 16, qj = (t & 15) * 4;
        size_t qoff = (size_t)qb * 64 + qj;
        f32x4 acc = (f32x4){0.f, 0.f, 0.f, 0.f};
        for (int s = 0; s < S; s++) {
            f32x4 p = *(const f32x4*)(opart + ((size_t)(s * 4 + b) * 128 + c) * 4096 + qoff);
#pragma unroll
            for (int j = 0; j < 4; j++) acc[j] += p[j];
        }
        f32x4 xv = *(const f32x4*)(x + ((size_t)b * 128 + c) * 4096 + qoff);
        f32x4 mv = *(const f32x4*)(mask + (size_t)b * 4096 + qoff);
        f32x4 res;
#pragma unroll
        for (int j = 0; j < 4; j++)
            res[j] = acc[j] * Linv[qj + j] * (1.f - mv[j]) * (1.f / 9.f) + xv[j] * mv[j];
        *(f32x4*)(out + ((size_t)b * 128 + c) * 4096 + qoff) = res;
    }
}

extern "C" void kernel_launch(void* const* d_in, const int* in_sizes, int n_in,
                              void* d_out, int out_size, void* d_ws, size_t ws_size,
                              hipStream_t stream) {
    const float* x = (const float*)d_in[0];     // f32 (4,128,64,64)
    const float* mask = (const float*)d_in[1];  // f32 (4,1,64,64)
    float* out = (float*)d_out;                 // f32 (4,128,64,64)
    char* ws = (char*)d_ws;
    unsigned short* kmat = (unsigned short*)(ws);
    unsigned short* kT   = (unsigned short*)(ws + (size_t)4 * 1024 * 1024);
    unsigned short* xbT  = (unsigned short*)(ws + (size_t)8 * 1024 * 1024);
    float* lsum  = (float*)(ws + (size_t)12 * 1024 * 1024);
    float* opart = (float*)(ws + (size_t)12 * 1024 * 1024 + 512 * 1024);

    // ws need: 12 MiB + 512 KiB + S*8 MiB
    int S;
    if (ws_size >= (size_t)46661632) S = 4;
    else if (ws_size >= (size_t)29884416) S = 2;
    else if (ws_size >= (size_t)21495808) S = 1;
    else return;

    prep_k<<<dim3(64, 4), 256, 0, stream>>>(x, kmat, kT);
    prep_xb<<<dim3(64, 4), 256, 0, stream>>>(x, xbT);
    // 1D grid: combo = id % (4S) keeps each (b,split) on one XCD (round-robin id%8)
    flash_attn<<<dim3(32 * 4 * S), 256, 0, stream>>>(kmat, kT, xbT, opart, lsum, S);
    combine<<<dim3(64, 4), 256, 0, stream>>>(opart, lsum, x, mask, out, S);
}